// Round 2
// baseline (1167.168 us; speedup 1.0000x reference)
//
#include <hip/hip_runtime.h>
#include <hip/hip_bf16.h>
#include <stdint.h>

// Problem dims (B=2, T=2048, H=1024, F=4096, E=8)
#define BT   4096
#define HDIM 1024
#define FDIM 4096
#define EDIM 8
#define TOPP 0.8f

typedef unsigned short u16;
typedef __attribute__((ext_vector_type(8))) short  short8;
typedef __attribute__((ext_vector_type(8))) unsigned short ushort8;
typedef __attribute__((ext_vector_type(4))) float  f32x4;

// ---------- helpers ----------
__device__ __forceinline__ u16 f2bf(float f) {
  uint32_t u = __builtin_bit_cast(uint32_t, f);
  uint32_t r = u + 0x7FFFu + ((u >> 16) & 1u);   // RNE
  return (u16)(r >> 16);
}

__device__ __forceinline__ void gload_lds16(const void* g, void* l) {
  __builtin_amdgcn_global_load_lds(
      (const __attribute__((address_space(1))) uint32_t*)g,
      (__attribute__((address_space(3))) uint32_t*)l, 16, 0, 0);
}

// Bijective XCD-aware swizzle (m204): contiguous grid chunk per XCD.
__device__ __forceinline__ int xcd_swizzle(int bid, int nwg) {
  const int nx = 8;
  int q = nwg / nx, r = nwg % nx;
  int xcd = bid % nx, lin = bid / nx;
  int base = (xcd < r) ? xcd * (q + 1) : r * (q + 1) + (xcd - r) * q;
  return base + lin;
}

// ---------- router: probs -> top-p gate (replicates stable argsort semantics) ----------
__global__ __launch_bounds__(256) void router_kernel(
    const float* __restrict__ x, const float* __restrict__ Wr,
    const float* __restrict__ br, float* __restrict__ gate) {
  const int wid  = threadIdx.x >> 6;
  const int lane = threadIdx.x & 63;
  const int token = blockIdx.x * 4 + wid;   // grid = BT/4
  const float* xr = x + (size_t)token * HDIM;

  float p[8] = {0.f,0.f,0.f,0.f,0.f,0.f,0.f,0.f};
  #pragma unroll
  for (int j = 0; j < 16; ++j) {
    int hh = lane * 16 + j;
    float xv = xr[hh];
    const float* wrow = Wr + (size_t)hh * 8;
    #pragma unroll
    for (int e = 0; e < 8; ++e) p[e] += xv * wrow[e];
  }
  #pragma unroll
  for (int off = 32; off > 0; off >>= 1) {
    #pragma unroll
    for (int e = 0; e < 8; ++e) p[e] += __shfl_xor(p[e], off, 64);
  }
  float mx = -1e30f;
  #pragma unroll
  for (int e = 0; e < 8; ++e) { p[e] += br[e]; mx = fmaxf(mx, p[e]); }
  float s = 0.f;
  #pragma unroll
  for (int e = 0; e < 8; ++e) { p[e] = expf(p[e] - mx); s += p[e]; }
  float inv = 1.0f / s;
  #pragma unroll
  for (int e = 0; e < 8; ++e) p[e] *= inv;

  if (lane == 0) {
    float g[8];
    #pragma unroll
    for (int e = 0; e < 8; ++e) {
      float pe = p[e];
      float cum = pe; int rank = 0;
      #pragma unroll
      for (int e2 = 0; e2 < 8; ++e2) {
        if (e2 == e) continue;
        bool before = (p[e2] > pe) || (p[e2] == pe && e2 < e);
        if (before) { cum += p[e2]; rank++; }
      }
      bool keep = (cum < TOPP) || (rank == 0);
      g[e] = keep ? pe : 0.f;
    }
    float* gp = gate + (size_t)token * 8;
    #pragma unroll
    for (int e = 0; e < 8; ++e) gp[e] = g[e];
  }
}

// ---------- cast x f32 -> bf16 ----------
__global__ __launch_bounds__(256) void cast_x_kernel(
    const float* __restrict__ in, u16* __restrict__ out) {
  int i = (blockIdx.x * 256 + threadIdx.x) * 8;
  float4 a = *(const float4*)(in + i);
  float4 b = *(const float4*)(in + i + 4);
  ushort8 o;
  o[0] = f2bf(a.x); o[1] = f2bf(a.y); o[2] = f2bf(a.z); o[3] = f2bf(a.w);
  o[4] = f2bf(b.x); o[5] = f2bf(b.y); o[6] = f2bf(b.z); o[7] = f2bf(b.w);
  *(ushort8*)(out + i) = o;
}

// ---------- transpose + cast: per-expert (R,C) f32 -> (C,R) bf16 ----------
__global__ __launch_bounds__(256) void transpose_cast_kernel(
    const float* __restrict__ in, u16* __restrict__ out, int R, int C) {
  __shared__ float tile[32][33];
  const int e = blockIdx.z;
  const float* ip = in + (size_t)e * R * C;
  u16* op = out + (size_t)e * R * C;
  int x  = blockIdx.x * 32 + threadIdx.x;   // C coord
  int y0 = blockIdx.y * 32;                 // R tile base
  int ty = threadIdx.y;                     // 0..7
  #pragma unroll
  for (int j = 0; j < 32; j += 8)
    tile[ty + j][threadIdx.x] = ip[(size_t)(y0 + ty + j) * C + x];
  __syncthreads();
  int xo  = y0 + threadIdx.x;               // R coord (contiguous on out)
  int yo0 = blockIdx.x * 32;
  #pragma unroll
  for (int j = 0; j < 32; j += 8)
    op[(size_t)(yo0 + ty + j) * R + xo] = f2bf(tile[threadIdx.x][ty + j]);
}

// ---------- GEMM: C(MxN) = A(MxK) * Bt(NxK)^T, bf16 in, f32 acc ----------
// EPI 0: Hout = bf16(relu(acc + bias[n]))
// EPI 1: Cout = gate[m][expert] * (acc + bias[n])         (write)
// EPI 2: Cout += gate[m][expert] * (acc + bias[n])        (accumulate)
template <int Ndim, int Kdim, int EPI>
__global__ __launch_bounds__(256) void gemm_kernel(
    const u16* __restrict__ A, const u16* __restrict__ Bt,
    const float* __restrict__ bias, const float* __restrict__ gate,
    int expert, u16* __restrict__ Hout, float* __restrict__ Cout) {
  __shared__ u16 Atile[128 * 32];
  __shared__ u16 Btile[128 * 32];

  const int tid  = threadIdx.x;
  const int wid  = tid >> 6;
  const int lane = tid & 63;

  // XCD-aware remap of the linear block id (T1): contiguous chunk per XCD
  const int NXT = Ndim / 128;               // N-tiles (fast dim)
  const int nwg = gridDim.x * gridDim.y;
  const int bid = xcd_swizzle(blockIdx.y * gridDim.x + blockIdx.x, nwg);
  const int bn = bid % NXT, bm = bid / NXT;

  const int wm = wid >> 1, wn = wid & 1;     // 2x2 waves, each 64x64
  const int l4  = lane >> 4;                 // 0..3
  const int l15 = lane & 15;

  f32x4 acc[4][4];
  #pragma unroll
  for (int i = 0; i < 4; ++i)
    #pragma unroll
    for (int j = 0; j < 4; ++j) acc[i][j] = {0.f, 0.f, 0.f, 0.f};

  const int srow = lane >> 2;        // 0..15 within 16-row chunk
  const int scol = (lane & 3) * 8;   // k offset (8 bf16 = 16B)
  const int rowA0 = bm * 128;
  const int rowB0 = bn * 128;

  for (int k0 = 0; k0 < Kdim; k0 += 32) {
    __syncthreads();   // all waves done reading LDS from previous iter
    #pragma unroll
    for (int i = 0; i < 2; ++i) {
      int c = wid * 2 + i;           // chunk 0..7 (16 rows each)
      const u16* ga = A  + (size_t)(rowA0 + c * 16 + srow) * Kdim + k0 + scol;
      gload_lds16(ga, &Atile[c * 512]);
      const u16* gb = Bt + (size_t)(rowB0 + c * 16 + srow) * Kdim + k0 + scol;
      gload_lds16(gb, &Btile[c * 512]);
    }
    __syncthreads();   // implies vmcnt(0): staged data visible

    short8 af[4], bf[4];
    #pragma unroll
    for (int mi = 0; mi < 4; ++mi)
      af[mi] = *(const short8*)&Atile[(wm * 64 + mi * 16 + l15) * 32 + l4 * 8];
    #pragma unroll
    for (int ni = 0; ni < 4; ++ni)
      bf[ni] = *(const short8*)&Btile[(wn * 64 + ni * 16 + l15) * 32 + l4 * 8];
    #pragma unroll
    for (int mi = 0; mi < 4; ++mi)
      #pragma unroll
      for (int ni = 0; ni < 4; ++ni)
        acc[mi][ni] = __builtin_amdgcn_mfma_f32_16x16x32_bf16(
            af[mi], bf[ni], acc[mi][ni], 0, 0, 0);
  }

  // epilogue
  const int cm0 = bm * 128 + wm * 64;
  const int cn0 = bn * 128 + wn * 64;
  float bv[4];
  #pragma unroll
  for (int ni = 0; ni < 4; ++ni) bv[ni] = bias[cn0 + ni * 16 + l15];

  #pragma unroll
  for (int mi = 0; mi < 4; ++mi) {
    #pragma unroll
    for (int r = 0; r < 4; ++r) {
      const int row = cm0 + mi * 16 + l4 * 4 + r;
      float gv = 0.f;
      if (EPI != 0) gv = gate[(size_t)row * 8 + expert];
      #pragma unroll
      for (int ni = 0; ni < 4; ++ni) {
        const int col = cn0 + ni * 16 + l15;
        float v = acc[mi][ni][r] + bv[ni];
        if (EPI == 0) {
          v = fmaxf(v, 0.f);
          Hout[(size_t)row * Ndim + col] = f2bf(v);
        } else if (EPI == 1) {
          Cout[(size_t)row * Ndim + col] = gv * v;
        } else {
          Cout[(size_t)row * Ndim + col] += gv * v;
        }
      }
    }
  }
}

// ---------- launch ----------
extern "C" void kernel_launch(void* const* d_in, const int* in_sizes, int n_in,
                              void* d_out, int out_size, void* d_ws, size_t ws_size,
                              hipStream_t stream) {
  const float* x  = (const float*)d_in[0];
  const float* Wr = (const float*)d_in[1];
  const float* br = (const float*)d_in[2];
  const float* W1 = (const float*)d_in[3];
  const float* b1 = (const float*)d_in[4];
  const float* W2 = (const float*)d_in[5];
  const float* b2 = (const float*)d_in[6];
  float* out = (float*)d_out;

  // workspace layout (~176 MB)
  char* p = (char*)d_ws;
  float* gate = (float*)p; p += (size_t)BT * EDIM * 4;
  u16* xb   = (u16*)p;     p += (size_t)BT * HDIM * 2;
  u16* w1t  = (u16*)p;     p += (size_t)EDIM * FDIM * HDIM * 2;   // (E,F,H)
  u16* w2t  = (u16*)p;     p += (size_t)EDIM * HDIM * FDIM * 2;   // (E,H,F)
  u16* h    = (u16*)p;     p += (size_t)BT * FDIM * 2;            // (BT,F) one expert

  router_kernel<<<BT / 4, 256, 0, stream>>>(x, Wr, br, gate);
  cast_x_kernel<<<(BT * HDIM) / (256 * 8), 256, 0, stream>>>(x, xb);
  // W1 (E,H,F) -> W1T (E,F,H)
  transpose_cast_kernel<<<dim3(FDIM / 32, HDIM / 32, EDIM), dim3(32, 8), 0, stream>>>(
      W1, w1t, HDIM, FDIM);
  // W2 (E,F,H) -> W2T (E,H,F)
  transpose_cast_kernel<<<dim3(HDIM / 32, FDIM / 32, EDIM), dim3(32, 8), 0, stream>>>(
      W2, w2t, FDIM, HDIM);

  for (int e = 0; e < EDIM; ++e) {
    // h = relu(x @ W1_e + b1_e)   (M=BT, N=F, K=H)
    gemm_kernel<FDIM, HDIM, 0><<<dim3(FDIM / 128, BT / 128), 256, 0, stream>>>(
        xb, w1t + (size_t)e * FDIM * HDIM, b1 + (size_t)e * FDIM,
        nullptr, 0, h, nullptr);
    // out (+)= gate_e * (h @ W2_e + b2_e)   (M=BT, N=H, K=F)
    if (e == 0) {
      gemm_kernel<HDIM, FDIM, 1><<<dim3(HDIM / 128, BT / 128), 256, 0, stream>>>(
          h, w2t + (size_t)e * HDIM * FDIM, b2 + (size_t)e * HDIM,
          gate, e, nullptr, out);
    } else {
      gemm_kernel<HDIM, FDIM, 2><<<dim3(HDIM / 128, BT / 128), 256, 0, stream>>>(
          h, w2t + (size_t)e * HDIM * FDIM, b2 + (size_t)e * HDIM,
          gate, e, nullptr, out);
    }
  }
}

// Round 3
// 734.152 us; speedup vs baseline: 1.5898x; 1.5898x over previous
//
#include <hip/hip_runtime.h>
#include <hip/hip_bf16.h>
#include <stdint.h>

// Problem dims (B=2, T=2048, H=1024, F=4096, E=8)
#define BT   4096
#define HDIM 1024
#define FDIM 4096
#define EDIM 8
#define TOPP 0.8f
#define KCAT (EDIM * FDIM)   // 32768 concatenated K for GEMM2

typedef unsigned short u16;
typedef __attribute__((ext_vector_type(8))) short  short8;
typedef __attribute__((ext_vector_type(8))) unsigned short ushort8;
typedef __attribute__((ext_vector_type(4))) float  f32x4;

// ---------- helpers ----------
__device__ __forceinline__ u16 f2bf(float f) {
  uint32_t u = __builtin_bit_cast(uint32_t, f);
  uint32_t r = u + 0x7FFFu + ((u >> 16) & 1u);   // RNE
  return (u16)(r >> 16);
}

__device__ __forceinline__ void gload_lds16(const void* g, void* l) {
  __builtin_amdgcn_global_load_lds(
      (const __attribute__((address_space(1))) uint32_t*)g,
      (__attribute__((address_space(3))) uint32_t*)l, 16, 0, 0);
}

#define VMWAIT4() asm volatile("s_waitcnt vmcnt(4)" ::: "memory")
#define VMWAIT0() asm volatile("s_waitcnt vmcnt(0)" ::: "memory")
#define BAR()     asm volatile("s_barrier" ::: "memory")

// Bijective XCD-aware swizzle (m204)
__device__ __forceinline__ int xcd_swizzle(int bid, int nwg) {
  const int nx = 8;
  int q = nwg / nx, r = nwg % nx;
  int xcd = bid % nx, lin = bid / nx;
  int base = (xcd < r) ? xcd * (q + 1) : r * (q + 1) + (xcd - r) * q;
  return base + lin;
}

// ---------- router: probs -> top-p gate (stable argsort semantics) ----------
__global__ __launch_bounds__(256) void router_kernel(
    const float* __restrict__ x, const float* __restrict__ Wr,
    const float* __restrict__ br, float* __restrict__ gate) {
  const int wid  = threadIdx.x >> 6;
  const int lane = threadIdx.x & 63;
  const int token = blockIdx.x * 4 + wid;
  const float* xr = x + (size_t)token * HDIM;

  float p[8] = {0.f,0.f,0.f,0.f,0.f,0.f,0.f,0.f};
  #pragma unroll
  for (int j = 0; j < 16; ++j) {
    int hh = lane * 16 + j;
    float xv = xr[hh];
    const float* wrow = Wr + (size_t)hh * 8;
    #pragma unroll
    for (int e = 0; e < 8; ++e) p[e] += xv * wrow[e];
  }
  #pragma unroll
  for (int off = 32; off > 0; off >>= 1) {
    #pragma unroll
    for (int e = 0; e < 8; ++e) p[e] += __shfl_xor(p[e], off, 64);
  }
  float mx = -1e30f;
  #pragma unroll
  for (int e = 0; e < 8; ++e) { p[e] += br[e]; mx = fmaxf(mx, p[e]); }
  float s = 0.f;
  #pragma unroll
  for (int e = 0; e < 8; ++e) { p[e] = expf(p[e] - mx); s += p[e]; }
  float inv = 1.0f / s;
  #pragma unroll
  for (int e = 0; e < 8; ++e) p[e] *= inv;

  if (lane == 0) {
    float g[8];
    #pragma unroll
    for (int e = 0; e < 8; ++e) {
      float pe = p[e];
      float cum = pe; int rank = 0;
      #pragma unroll
      for (int e2 = 0; e2 < 8; ++e2) {
        if (e2 == e) continue;
        bool before = (p[e2] > pe) || (p[e2] == pe && e2 < e);
        if (before) { cum += p[e2]; rank++; }
      }
      bool keep = (cum < TOPP) || (rank == 0);
      g[e] = keep ? pe : 0.f;
    }
    float* gp = gate + (size_t)token * 8;
    #pragma unroll
    for (int e = 0; e < 8; ++e) gp[e] = g[e];
  }
}

// ---------- cast x f32 -> bf16 ----------
__global__ __launch_bounds__(256) void cast_x_kernel(
    const float* __restrict__ in, u16* __restrict__ out) {
  int i = (blockIdx.x * 256 + threadIdx.x) * 8;
  float4 a = *(const float4*)(in + i);
  float4 b = *(const float4*)(in + i + 4);
  ushort8 o;
  o[0] = f2bf(a.x); o[1] = f2bf(a.y); o[2] = f2bf(a.z); o[3] = f2bf(a.w);
  o[4] = f2bf(b.x); o[5] = f2bf(b.y); o[6] = f2bf(b.z); o[7] = f2bf(b.w);
  *(ushort8*)(out + i) = o;
}

// ---------- transpose + cast: per-expert (R,C) f32 -> out[e*estride + c*rstride + r] bf16
__global__ __launch_bounds__(256) void transpose_cast_kernel(
    const float* __restrict__ in, u16* __restrict__ out, int R, int C,
    size_t rstride, size_t estride) {
  __shared__ float tile[32][33];
  const int e = blockIdx.z;
  const float* ip = in + (size_t)e * R * C;
  u16* op = out + (size_t)e * estride;
  int x  = blockIdx.x * 32 + threadIdx.x;   // C coord
  int y0 = blockIdx.y * 32;                 // R tile base
  int ty = threadIdx.y;                     // 0..7
  #pragma unroll
  for (int j = 0; j < 32; j += 8)
    tile[ty + j][threadIdx.x] = ip[(size_t)(y0 + ty + j) * C + x];
  __syncthreads();
  int xo  = y0 + threadIdx.x;               // R coord (contiguous on out)
  int yo0 = blockIdx.x * 32;
  #pragma unroll
  for (int j = 0; j < 32; j += 8)
    op[(size_t)(yo0 + ty + j) * rstride + xo] = f2bf(tile[threadIdx.x][ty + j]);
}

// ======================================================================
// 256x256-tile GEMM, BK=32, 8 waves (2M x 4N), ring-of-4 LDS slots,
// counted vmcnt(4), 1 barrier/iter, source-preswizzled LDS (XOR row&3).
// MODE 0 (GEMM1): C = A(BT,H) x W1_e^T -> h_all[row, e*F+col] = bf16(gate*relu(acc+b1))
// MODE 1 (GEMM2): C = A'(BT,KCAT) x B'^T, K-split z -> part[z] f32 (no bias)
// ======================================================================
template <int MODE>
__global__ __launch_bounds__(512, 2) void gemm256(
    const u16* __restrict__ A0, const u16* __restrict__ B0,
    const float* __restrict__ bias, const float* __restrict__ gate,
    u16* __restrict__ hout, float* __restrict__ part) {
  __shared__ u16 lds[4 * 2 * 8192];   // [slot][A/B][16KB] = 128 KiB

  constexpr int NXT  = (MODE == 0 ? 16 : 4);
  constexpr int NYT  = 16;
  constexpr int NZ   = (MODE == 0 ? 8 : 4);
  constexpr int NT   = (MODE == 0 ? HDIM / 32 : (KCAT / NZ) / 32);  // 32 / 256
  const size_t Kstr  = (MODE == 0 ? (size_t)HDIM : (size_t)KCAT);

  const int tid  = threadIdx.x;
  const int wid  = tid >> 6;
  const int lane = tid & 63;

  int lin = (blockIdx.z * gridDim.y + blockIdx.y) * gridDim.x + blockIdx.x;
  lin = xcd_swizzle(lin, NXT * NYT * NZ);
  const int bn = lin % NXT; lin /= NXT;
  const int bm = lin % NYT; lin /= NYT;
  const int bz = lin;                       // expert (MODE0) or k-split (MODE1)

  const u16* Abase = A0 + (size_t)bm * 256 * Kstr
                        + (MODE == 0 ? 0 : (size_t)bz * (KCAT / NZ));
  const u16* Bbase = (MODE == 0 ? B0 + (size_t)bz * FDIM * HDIM
                                : B0 + (size_t)bz * (KCAT / NZ))
                        + (size_t)bn * 256 * Kstr;

  // staging addresses: wave w handles A chunks {2w,2w+1} and B chunks {2w,2w+1}
  const int rr = lane >> 2;                         // 0..15 row within chunk
  const int sc = (((lane & 3) ^ (rr & 3)) * 8);     // pre-swizzled source col
  const u16* gp[4];
  gp[0] = Abase + (size_t)((2 * wid + 0) * 16 + rr) * Kstr + sc;
  gp[1] = Abase + (size_t)((2 * wid + 1) * 16 + rr) * Kstr + sc;
  gp[2] = Bbase + (size_t)((2 * wid + 0) * 16 + rr) * Kstr + sc;
  gp[3] = Bbase + (size_t)((2 * wid + 1) * 16 + rr) * Kstr + sc;
  const int ldc0 = (2 * wid + 0) * 512;             // chunk LDS offset (u16)
  const int ldc1 = (2 * wid + 1) * 512;

  #define STAGE(T) do {                                                   \
    const int _s = (T) & 3; const size_t _k = (size_t)(T) * 32;           \
    gload_lds16(gp[0] + _k, &lds[_s * 16384 + ldc0]);                     \
    gload_lds16(gp[1] + _k, &lds[_s * 16384 + ldc1]);                     \
    gload_lds16(gp[2] + _k, &lds[_s * 16384 + 8192 + ldc0]);              \
    gload_lds16(gp[3] + _k, &lds[_s * 16384 + 8192 + ldc1]);              \
  } while (0)

  const int wm = wid >> 2, wn = wid & 3;   // 2M x 4N waves, each 128x64
  const int l4 = lane >> 4, l15 = lane & 15;

  f32x4 acc[8][4];
  #pragma unroll
  for (int i = 0; i < 8; ++i)
    #pragma unroll
    for (int j = 0; j < 4; ++j) acc[i][j] = {0.f, 0.f, 0.f, 0.f};

  // precomputed swizzled LDS read offsets (u16 units)
  int aoff[8], boff[4];
  #pragma unroll
  for (int mi = 0; mi < 8; ++mi) {
    int row = wm * 128 + mi * 16 + l15;
    aoff[mi] = row * 32 + (l4 ^ (row & 3)) * 8;
  }
  #pragma unroll
  for (int ni = 0; ni < 4; ++ni) {
    int row = wn * 64 + ni * 16 + l15;
    boff[ni] = 8192 + row * 32 + (l4 ^ (row & 3)) * 8;
  }

  #define COMPUTE(T) do {                                                 \
    const int _sb = ((T) & 3) * 16384;                                    \
    short8 a_[8], b_[4];                                                  \
    _Pragma("unroll")                                                     \
    for (int mi = 0; mi < 8; ++mi)                                        \
      a_[mi] = *(const short8*)&lds[_sb + aoff[mi]];                      \
    _Pragma("unroll")                                                     \
    for (int ni = 0; ni < 4; ++ni)                                        \
      b_[ni] = *(const short8*)&lds[_sb + boff[ni]];                      \
    __builtin_amdgcn_s_setprio(1);                                        \
    _Pragma("unroll")                                                     \
    for (int mi = 0; mi < 8; ++mi)                                        \
      _Pragma("unroll")                                                   \
      for (int ni = 0; ni < 4; ++ni)                                      \
        acc[mi][ni] = __builtin_amdgcn_mfma_f32_16x16x32_bf16(            \
            a_[mi], b_[ni], acc[mi][ni], 0, 0, 0);                        \
    __builtin_amdgcn_s_setprio(0);                                        \
  } while (0)

  // prologue: stage tiles 0,1 (8 loads/wave outstanding)
  STAGE(0);
  STAGE(1);
  for (int T = 0; T < NT - 1; ++T) {
    VMWAIT4();            // tile T's 4 loads done; T+1's may remain in flight
    BAR();                // all waves confirmed -> tile T fully visible
    if (T + 2 < NT) STAGE(T + 2);   // ring slot (T+2)&3: last read at iter T-2
    COMPUTE(T);
  }
  VMWAIT0();
  BAR();
  COMPUTE(NT - 1);

  // ---------------- epilogue ----------------
  const int rowbase = bm * 256 + wm * 128;
  const int colbase = bn * 256 + wn * 64;

  if constexpr (MODE == 0) {
    float bv[4];
    #pragma unroll
    for (int ni = 0; ni < 4; ++ni)
      bv[ni] = bias[(size_t)bz * FDIM + colbase + ni * 16 + l15];
    #pragma unroll
    for (int mi = 0; mi < 8; ++mi) {
      #pragma unroll
      for (int r = 0; r < 4; ++r) {
        const int row = rowbase + mi * 16 + l4 * 4 + r;
        const float gv = gate[(size_t)row * 8 + bz];
        #pragma unroll
        for (int ni = 0; ni < 4; ++ni) {
          const int col = colbase + ni * 16 + l15;
          float v = fmaxf(acc[mi][ni][r] + bv[ni], 0.f);
          hout[(size_t)row * KCAT + (size_t)bz * FDIM + col] = f2bf(gv * v);
        }
      }
    }
  } else {
    float* pp = part + (size_t)bz * BT * HDIM;
    #pragma unroll
    for (int mi = 0; mi < 8; ++mi) {
      #pragma unroll
      for (int r = 0; r < 4; ++r) {
        const int row = rowbase + mi * 16 + l4 * 4 + r;
        #pragma unroll
        for (int ni = 0; ni < 4; ++ni) {
          const int col = colbase + ni * 16 + l15;
          pp[(size_t)row * HDIM + col] = acc[mi][ni][r];
        }
      }
    }
  }
  #undef STAGE
  #undef COMPUTE
}

// ---------- reduce: out = sum_z part[z] + sum_e gate[row][e]*b2[e][col] ----------
__global__ __launch_bounds__(256) void reduce_kernel(
    const float* __restrict__ part, const float* __restrict__ gate,
    const float* __restrict__ b2, float* __restrict__ out) {
  const int i = (blockIdx.x * 256 + threadIdx.x) * 4;
  const int row = i >> 10, col = i & 1023;
  float4 s = *(const float4*)(part + i);
  #pragma unroll
  for (int z = 1; z < 4; ++z) {
    float4 t = *(const float4*)(part + (size_t)z * BT * HDIM + i);
    s.x += t.x; s.y += t.y; s.z += t.z; s.w += t.w;
  }
  const float* g = gate + (size_t)row * 8;
  #pragma unroll
  for (int e = 0; e < 8; ++e) {
    float ge = g[e];
    float4 bv = *(const float4*)(b2 + (size_t)e * HDIM + col);
    s.x += ge * bv.x; s.y += ge * bv.y; s.z += ge * bv.z; s.w += ge * bv.w;
  }
  *(float4*)(out + i) = s;
}

// ======================================================================
// Fallback (R2-proven): 128x128-tile per-expert GEMMs, used if ws too small
// ======================================================================
template <int Ndim, int Kdim, int EPI>
__global__ __launch_bounds__(256) void gemm_fb(
    const u16* __restrict__ A, const u16* __restrict__ Bt,
    const float* __restrict__ bias, const float* __restrict__ gate,
    int expert, u16* __restrict__ Hout, float* __restrict__ Cout) {
  __shared__ u16 Atile[128 * 32];
  __shared__ u16 Btile[128 * 32];
  const int tid  = threadIdx.x;
  const int wid  = tid >> 6;
  const int lane = tid & 63;
  const int NXT = Ndim / 128;
  const int nwg = gridDim.x * gridDim.y;
  const int bid = xcd_swizzle(blockIdx.y * gridDim.x + blockIdx.x, nwg);
  const int bn = bid % NXT, bm = bid / NXT;
  const int wm = wid >> 1, wn = wid & 1;
  const int l4  = lane >> 4, l15 = lane & 15;
  f32x4 acc[4][4];
  #pragma unroll
  for (int i = 0; i < 4; ++i)
    #pragma unroll
    for (int j = 0; j < 4; ++j) acc[i][j] = {0.f, 0.f, 0.f, 0.f};
  const int srow = lane >> 2;
  const int scol = (lane & 3) * 8;
  for (int k0 = 0; k0 < Kdim; k0 += 32) {
    __syncthreads();
    #pragma unroll
    for (int i = 0; i < 2; ++i) {
      int c = wid * 2 + i;
      gload_lds16(A  + (size_t)(bm * 128 + c * 16 + srow) * Kdim + k0 + scol, &Atile[c * 512]);
      gload_lds16(Bt + (size_t)(bn * 128 + c * 16 + srow) * Kdim + k0 + scol, &Btile[c * 512]);
    }
    __syncthreads();
    short8 af[4], bf[4];
    #pragma unroll
    for (int mi = 0; mi < 4; ++mi)
      af[mi] = *(const short8*)&Atile[(wm * 64 + mi * 16 + l15) * 32 + l4 * 8];
    #pragma unroll
    for (int ni = 0; ni < 4; ++ni)
      bf[ni] = *(const short8*)&Btile[(wn * 64 + ni * 16 + l15) * 32 + l4 * 8];
    #pragma unroll
    for (int mi = 0; mi < 4; ++mi)
      #pragma unroll
      for (int ni = 0; ni < 4; ++ni)
        acc[mi][ni] = __builtin_amdgcn_mfma_f32_16x16x32_bf16(af[mi], bf[ni], acc[mi][ni], 0, 0, 0);
  }
  const int cm0 = bm * 128 + wm * 64;
  const int cn0 = bn * 128 + wn * 64;
  float bv[4];
  #pragma unroll
  for (int ni = 0; ni < 4; ++ni) bv[ni] = bias[cn0 + ni * 16 + l15];
  #pragma unroll
  for (int mi = 0; mi < 4; ++mi) {
    #pragma unroll
    for (int r = 0; r < 4; ++r) {
      const int row = cm0 + mi * 16 + l4 * 4 + r;
      float gv = 0.f;
      if (EPI != 0) gv = gate[(size_t)row * 8 + expert];
      #pragma unroll
      for (int ni = 0; ni < 4; ++ni) {
        const int col = cn0 + ni * 16 + l15;
        float v = acc[mi][ni][r] + bv[ni];
        if (EPI == 0)      Hout[(size_t)row * Ndim + col] = f2bf(fmaxf(v, 0.f));
        else if (EPI == 1) Cout[(size_t)row * Ndim + col] = gv * v;
        else               Cout[(size_t)row * Ndim + col] += gv * v;
      }
    }
  }
}

// ---------- launch ----------
extern "C" void kernel_launch(void* const* d_in, const int* in_sizes, int n_in,
                              void* d_out, int out_size, void* d_ws, size_t ws_size,
                              hipStream_t stream) {
  const float* x  = (const float*)d_in[0];
  const float* Wr = (const float*)d_in[1];
  const float* br = (const float*)d_in[2];
  const float* W1 = (const float*)d_in[3];
  const float* b1 = (const float*)d_in[4];
  const float* W2 = (const float*)d_in[5];
  const float* b2 = (const float*)d_in[6];
  float* out = (float*)d_out;

  const size_t sz_gate = (size_t)BT * EDIM * 4;            // 128 KB
  const size_t sz_xb   = (size_t)BT * HDIM * 2;            // 8 MB
  const size_t sz_w1t  = (size_t)EDIM * FDIM * HDIM * 2;   // 64 MB
  const size_t sz_w2t  = (size_t)EDIM * HDIM * FDIM * 2;   // 64 MB
  const size_t sz_hall = (size_t)BT * KCAT * 2;            // 256 MB
  const size_t need_primary = sz_gate + sz_xb + sz_w1t + sz_w2t + sz_hall;

  char* p = (char*)d_ws;
  float* gate = (float*)p; p += sz_gate;
  u16* xb   = (u16*)p;     p += sz_xb;
  u16* w1t  = (u16*)p;     char* w1t_region = (char*)w1t; p += sz_w1t;
  u16* w2t  = (u16*)p;     p += sz_w2t;

  router_kernel<<<BT / 4, 256, 0, stream>>>(x, Wr, br, gate);
  cast_x_kernel<<<(BT * HDIM) / (256 * 8), 256, 0, stream>>>(x, xb);
  // W1 (E,H,F) -> w1t[e][f][h]  (rstride=H, estride=F*H)
  transpose_cast_kernel<<<dim3(FDIM / 32, HDIM / 32, EDIM), dim3(32, 8), 0, stream>>>(
      W1, w1t, HDIM, FDIM, HDIM, (size_t)FDIM * HDIM);

  if (ws_size >= need_primary) {
    u16* h_all = (u16*)p;                       // (BT, KCAT) bf16
    float* part = (float*)w1t_region;           // 4 x (BT,H) f32, aliases w1t after G1
    // W2 (E,F,H) -> B'[n][e*F+f]  (rstride=KCAT, estride=F)
    transpose_cast_kernel<<<dim3(HDIM / 32, FDIM / 32, EDIM), dim3(32, 8), 0, stream>>>(
        W2, w2t, FDIM, HDIM, KCAT, FDIM);
    // GEMM1: all experts, h_all[row, e*F+col] = bf16(gate*relu(x@W1_e + b1_e))
    gemm256<0><<<dim3(16, 16, 8), 512, 0, stream>>>(xb, w1t, b1, gate, h_all, nullptr);
    // GEMM2: (g.h) @ concat(W2), split-K x4 -> part
    gemm256<1><<<dim3(4, 16, 4), 512, 0, stream>>>(h_all, w2t, nullptr, nullptr, nullptr, part);
    // out = sum_z part + sum_e g_e * b2_e
    reduce_kernel<<<(BT * HDIM) / (256 * 4), 256, 0, stream>>>(part, gate, b2, out);
  } else {
    // -------- fallback: R2-proven path --------
    u16* h = (u16*)p;   // (BT, F) one expert, 32 MB
    transpose_cast_kernel<<<dim3(HDIM / 32, FDIM / 32, EDIM), dim3(32, 8), 0, stream>>>(
        W2, w2t, FDIM, HDIM, FDIM, (size_t)HDIM * FDIM);
    for (int e = 0; e < EDIM; ++e) {
      gemm_fb<FDIM, HDIM, 0><<<dim3(FDIM / 128, BT / 128), 256, 0, stream>>>(
          xb, w1t + (size_t)e * FDIM * HDIM, b1 + (size_t)e * FDIM, nullptr, 0, h, nullptr);
      if (e == 0)
        gemm_fb<HDIM, FDIM, 1><<<dim3(HDIM / 128, BT / 128), 256, 0, stream>>>(
            h, w2t + (size_t)e * HDIM * FDIM, b2 + (size_t)e * HDIM, gate, e, nullptr, out);
      else
        gemm_fb<HDIM, FDIM, 2><<<dim3(HDIM / 128, BT / 128), 256, 0, stream>>>(
            h, w2t + (size_t)e * HDIM * FDIM, b2 + (size_t)e * HDIM, gate, e, nullptr, out);
    }
  }
}

// Round 4
// 726.286 us; speedup vs baseline: 1.6070x; 1.0108x over previous
//
#include <hip/hip_runtime.h>
#include <hip/hip_bf16.h>
#include <stdint.h>

// Problem dims (B=2, T=2048, H=1024, F=4096, E=8)
#define BT   4096
#define HDIM 1024
#define FDIM 4096
#define EDIM 8
#define TOPP 0.8f
#define KCAT (EDIM * FDIM)   // 32768 concatenated K for GEMM2

typedef unsigned short u16;
typedef __attribute__((ext_vector_type(8))) short  short8;
typedef __attribute__((ext_vector_type(8))) unsigned short ushort8;
typedef __attribute__((ext_vector_type(4))) float  f32x4;

// ---------- helpers ----------
__device__ __forceinline__ u16 f2bf(float f) {
  uint32_t u = __builtin_bit_cast(uint32_t, f);
  uint32_t r = u + 0x7FFFu + ((u >> 16) & 1u);   // RNE
  return (u16)(r >> 16);
}

__device__ __forceinline__ void gload_lds16(const void* g, void* l) {
  __builtin_amdgcn_global_load_lds(
      (const __attribute__((address_space(1))) uint32_t*)g,
      (__attribute__((address_space(3))) uint32_t*)l, 16, 0, 0);
}

#define VMWAIT8() asm volatile("s_waitcnt vmcnt(8)" ::: "memory")
#define VMWAIT4() asm volatile("s_waitcnt vmcnt(4)" ::: "memory")
#define VMWAIT0() asm volatile("s_waitcnt vmcnt(0)" ::: "memory")
#define BAR()     asm volatile("s_barrier" ::: "memory")

// Bijective XCD-aware swizzle (m204)
__device__ __forceinline__ int xcd_swizzle(int bid, int nwg) {
  const int nx = 8;
  int q = nwg / nx, r = nwg % nx;
  int xcd = bid % nx, lin = bid / nx;
  int base = (xcd < r) ? xcd * (q + 1) : r * (q + 1) + (xcd - r) * q;
  return base + lin;
}

// ---------- router: probs -> top-p gate (stable argsort semantics) ----------
__global__ __launch_bounds__(256) void router_kernel(
    const float* __restrict__ x, const float* __restrict__ Wr,
    const float* __restrict__ br, float* __restrict__ gate) {
  const int wid  = threadIdx.x >> 6;
  const int lane = threadIdx.x & 63;
  const int token = blockIdx.x * 4 + wid;
  const float* xr = x + (size_t)token * HDIM;

  float p[8] = {0.f,0.f,0.f,0.f,0.f,0.f,0.f,0.f};
  #pragma unroll
  for (int j = 0; j < 16; ++j) {
    int hh = lane * 16 + j;
    float xv = xr[hh];
    const float* wrow = Wr + (size_t)hh * 8;
    #pragma unroll
    for (int e = 0; e < 8; ++e) p[e] += xv * wrow[e];
  }
  #pragma unroll
  for (int off = 32; off > 0; off >>= 1) {
    #pragma unroll
    for (int e = 0; e < 8; ++e) p[e] += __shfl_xor(p[e], off, 64);
  }
  float mx = -1e30f;
  #pragma unroll
  for (int e = 0; e < 8; ++e) { p[e] += br[e]; mx = fmaxf(mx, p[e]); }
  float s = 0.f;
  #pragma unroll
  for (int e = 0; e < 8; ++e) { p[e] = expf(p[e] - mx); s += p[e]; }
  float inv = 1.0f / s;
  #pragma unroll
  for (int e = 0; e < 8; ++e) p[e] *= inv;

  if (lane == 0) {
    float g[8];
    #pragma unroll
    for (int e = 0; e < 8; ++e) {
      float pe = p[e];
      float cum = pe; int rank = 0;
      #pragma unroll
      for (int e2 = 0; e2 < 8; ++e2) {
        if (e2 == e) continue;
        bool before = (p[e2] > pe) || (p[e2] == pe && e2 < e);
        if (before) { cum += p[e2]; rank++; }
      }
      bool keep = (cum < TOPP) || (rank == 0);
      g[e] = keep ? pe : 0.f;
    }
    float* gp = gate + (size_t)token * 8;
    #pragma unroll
    for (int e = 0; e < 8; ++e) gp[e] = g[e];
  }
}

// ---------- cast x f32 -> bf16 ----------
__global__ __launch_bounds__(256) void cast_x_kernel(
    const float* __restrict__ in, u16* __restrict__ out) {
  int i = (blockIdx.x * 256 + threadIdx.x) * 8;
  float4 a = *(const float4*)(in + i);
  float4 b = *(const float4*)(in + i + 4);
  ushort8 o;
  o[0] = f2bf(a.x); o[1] = f2bf(a.y); o[2] = f2bf(a.z); o[3] = f2bf(a.w);
  o[4] = f2bf(b.x); o[5] = f2bf(b.y); o[6] = f2bf(b.z); o[7] = f2bf(b.w);
  *(ushort8*)(out + i) = o;
}

// ---------- transpose + cast: per-expert (R,C) f32 -> out[e*estride + c*rstride + r] bf16
__global__ __launch_bounds__(256) void transpose_cast_kernel(
    const float* __restrict__ in, u16* __restrict__ out, int R, int C,
    size_t rstride, size_t estride) {
  __shared__ float tile[32][33];
  const int e = blockIdx.z;
  const float* ip = in + (size_t)e * R * C;
  u16* op = out + (size_t)e * estride;
  int x  = blockIdx.x * 32 + threadIdx.x;   // C coord
  int y0 = blockIdx.y * 32;                 // R tile base
  int ty = threadIdx.y;                     // 0..7
  #pragma unroll
  for (int j = 0; j < 32; j += 8)
    tile[ty + j][threadIdx.x] = ip[(size_t)(y0 + ty + j) * C + x];
  __syncthreads();
  int xo  = y0 + threadIdx.x;               // R coord (contiguous on out)
  int yo0 = blockIdx.x * 32;
  #pragma unroll
  for (int j = 0; j < 32; j += 8)
    op[(size_t)(yo0 + ty + j) * rstride + xo] = f2bf(tile[threadIdx.x][ty + j]);
}

// ======================================================================
// 256x256-tile GEMM, BK=32, 8 waves (2M x 4N), ring-of-4 LDS slots,
// depth-3 prefetch, counted vmcnt(8), 1 barrier/iter,
// source-preswizzled LDS (XOR (row>>1)&3 -> conflict-free b128 reads).
// MODE 0 (GEMM1): C = A(BT,H) x W1_e^T -> h_all[row, e*F+col] = bf16(gate*relu(acc+b1))
// MODE 1 (GEMM2): C = A'(BT,KCAT) x B'^T, K-split z -> part[z] f32 (no bias)
// ======================================================================
template <int MODE>
__global__ __launch_bounds__(512, 2) void gemm256(
    const u16* __restrict__ A0, const u16* __restrict__ B0,
    const float* __restrict__ bias, const float* __restrict__ gate,
    u16* __restrict__ hout, float* __restrict__ part) {
  __shared__ u16 lds[4 * 2 * 8192];   // [slot][A/B][16KB] = 128 KiB

  constexpr int NXT  = (MODE == 0 ? 16 : 4);
  constexpr int NYT  = 16;
  constexpr int NZ   = (MODE == 0 ? 8 : 4);
  constexpr int NT   = (MODE == 0 ? HDIM / 32 : (KCAT / NZ) / 32);  // 32 / 256
  const size_t Kstr  = (MODE == 0 ? (size_t)HDIM : (size_t)KCAT);

  const int tid  = threadIdx.x;
  const int wid  = tid >> 6;
  const int lane = tid & 63;

  int lin = (blockIdx.z * gridDim.y + blockIdx.y) * gridDim.x + blockIdx.x;
  lin = xcd_swizzle(lin, NXT * NYT * NZ);
  const int bn = lin % NXT; lin /= NXT;
  const int bm = lin % NYT; lin /= NYT;
  const int bz = lin;                       // expert (MODE0) or k-split (MODE1)

  const u16* Abase = A0 + (size_t)bm * 256 * Kstr
                        + (MODE == 0 ? 0 : (size_t)bz * (KCAT / NZ));
  const u16* Bbase = (MODE == 0 ? B0 + (size_t)bz * FDIM * HDIM
                                : B0 + (size_t)bz * (KCAT / NZ))
                        + (size_t)bn * 256 * Kstr;

  // staging addresses: wave w handles A chunks {2w,2w+1} and B chunks {2w,2w+1}
  const int rr = lane >> 2;                         // 0..15 row within chunk
  const int sc = (((lane & 3) ^ ((rr >> 1) & 3)) * 8);  // pre-swizzled source col
  const u16* gp[4];
  gp[0] = Abase + (size_t)((2 * wid + 0) * 16 + rr) * Kstr + sc;
  gp[1] = Abase + (size_t)((2 * wid + 1) * 16 + rr) * Kstr + sc;
  gp[2] = Bbase + (size_t)((2 * wid + 0) * 16 + rr) * Kstr + sc;
  gp[3] = Bbase + (size_t)((2 * wid + 1) * 16 + rr) * Kstr + sc;
  const int ldc0 = (2 * wid + 0) * 512;             // chunk LDS offset (u16)
  const int ldc1 = (2 * wid + 1) * 512;

  #define STAGE(T) do {                                                   \
    const int _s = (T) & 3; const size_t _k = (size_t)(T) * 32;           \
    gload_lds16(gp[0] + _k, &lds[_s * 16384 + ldc0]);                     \
    gload_lds16(gp[1] + _k, &lds[_s * 16384 + ldc1]);                     \
    gload_lds16(gp[2] + _k, &lds[_s * 16384 + 8192 + ldc0]);              \
    gload_lds16(gp[3] + _k, &lds[_s * 16384 + 8192 + ldc1]);              \
  } while (0)

  const int wm = wid >> 2, wn = wid & 3;   // 2M x 4N waves, each 128x64
  const int l4 = lane >> 4, l15 = lane & 15;

  f32x4 acc[8][4];
  #pragma unroll
  for (int i = 0; i < 8; ++i)
    #pragma unroll
    for (int j = 0; j < 4; ++j) acc[i][j] = {0.f, 0.f, 0.f, 0.f};

  // precomputed swizzled LDS read offsets (u16 units)
  int aoff[8], boff[4];
  #pragma unroll
  for (int mi = 0; mi < 8; ++mi) {
    int row = wm * 128 + mi * 16 + l15;
    aoff[mi] = row * 32 + (l4 ^ ((row >> 1) & 3)) * 8;
  }
  #pragma unroll
  for (int ni = 0; ni < 4; ++ni) {
    int row = wn * 64 + ni * 16 + l15;
    boff[ni] = 8192 + row * 32 + (l4 ^ ((row >> 1) & 3)) * 8;
  }

  #define COMPUTE(T) do {                                                 \
    const int _sb = ((T) & 3) * 16384;                                    \
    short8 a_[8], b_[4];                                                  \
    _Pragma("unroll")                                                     \
    for (int mi = 0; mi < 8; ++mi)                                        \
      a_[mi] = *(const short8*)&lds[_sb + aoff[mi]];                      \
    _Pragma("unroll")                                                     \
    for (int ni = 0; ni < 4; ++ni)                                        \
      b_[ni] = *(const short8*)&lds[_sb + boff[ni]];                      \
    __builtin_amdgcn_s_setprio(1);                                        \
    _Pragma("unroll")                                                     \
    for (int mi = 0; mi < 8; ++mi)                                        \
      _Pragma("unroll")                                                   \
      for (int ni = 0; ni < 4; ++ni)                                      \
        acc[mi][ni] = __builtin_amdgcn_mfma_f32_16x16x32_bf16(            \
            a_[mi], b_[ni], acc[mi][ni], 0, 0, 0);                        \
    __builtin_amdgcn_s_setprio(0);                                        \
  } while (0)

  // prologue: stage tiles 0,1,2 (12 loads/wave outstanding)
  STAGE(0);
  STAGE(1);
  STAGE(2);
  for (int T = 0; T < NT - 3; ++T) {
    VMWAIT8();            // 12 outstanding -> drain to 8: tile T's loads done
    BAR();                // all waves confirmed -> tile T fully visible
    STAGE(T + 3);         // ring slot (T+3)&3 = (T-1)&3: reads finished pre-barrier
    COMPUTE(T);
  }
  // peeled tail: T = NT-3, NT-2, NT-1 (no more stages; counted waits shrink)
  VMWAIT8();  BAR();  COMPUTE(NT - 3);
  VMWAIT4();  BAR();  COMPUTE(NT - 2);
  VMWAIT0();  BAR();  COMPUTE(NT - 1);

  // ---------------- epilogue ----------------
  const int rowbase = bm * 256 + wm * 128;
  const int colbase = bn * 256 + wn * 64;

  if constexpr (MODE == 0) {
    float bv[4];
    #pragma unroll
    for (int ni = 0; ni < 4; ++ni)
      bv[ni] = bias[(size_t)bz * FDIM + colbase + ni * 16 + l15];
    #pragma unroll
    for (int mi = 0; mi < 8; ++mi) {
      #pragma unroll
      for (int r = 0; r < 4; ++r) {
        const int row = rowbase + mi * 16 + l4 * 4 + r;
        const float gv = gate[(size_t)row * 8 + bz];
        #pragma unroll
        for (int ni = 0; ni < 4; ++ni) {
          const int col = colbase + ni * 16 + l15;
          float v = fmaxf(acc[mi][ni][r] + bv[ni], 0.f);
          hout[(size_t)row * KCAT + (size_t)bz * FDIM + col] = f2bf(gv * v);
        }
      }
    }
  } else {
    float* pp = part + (size_t)bz * BT * HDIM;
    #pragma unroll
    for (int mi = 0; mi < 8; ++mi) {
      #pragma unroll
      for (int r = 0; r < 4; ++r) {
        const int row = rowbase + mi * 16 + l4 * 4 + r;
        #pragma unroll
        for (int ni = 0; ni < 4; ++ni) {
          const int col = colbase + ni * 16 + l15;
          pp[(size_t)row * HDIM + col] = acc[mi][ni][r];
        }
      }
    }
  }
  #undef STAGE
  #undef COMPUTE
}

// ---------- reduce: out = sum_z part[z] + sum_e gate[row][e]*b2[e][col] ----------
__global__ __launch_bounds__(256) void reduce_kernel(
    const float* __restrict__ part, const float* __restrict__ gate,
    const float* __restrict__ b2, float* __restrict__ out) {
  const int i = (blockIdx.x * 256 + threadIdx.x) * 4;
  const int row = i >> 10, col = i & 1023;
  float4 s = *(const float4*)(part + i);
  #pragma unroll
  for (int z = 1; z < 4; ++z) {
    float4 t = *(const float4*)(part + (size_t)z * BT * HDIM + i);
    s.x += t.x; s.y += t.y; s.z += t.z; s.w += t.w;
  }
  const float* g = gate + (size_t)row * 8;
  #pragma unroll
  for (int e = 0; e < 8; ++e) {
    float ge = g[e];
    float4 bv = *(const float4*)(b2 + (size_t)e * HDIM + col);
    s.x += ge * bv.x; s.y += ge * bv.y; s.z += ge * bv.z; s.w += ge * bv.w;
  }
  *(float4*)(out + i) = s;
}

// ======================================================================
// Fallback (R2-proven): 128x128-tile per-expert GEMMs, used if ws too small
// ======================================================================
template <int Ndim, int Kdim, int EPI>
__global__ __launch_bounds__(256) void gemm_fb(
    const u16* __restrict__ A, const u16* __restrict__ Bt,
    const float* __restrict__ bias, const float* __restrict__ gate,
    int expert, u16* __restrict__ Hout, float* __restrict__ Cout) {
  __shared__ u16 Atile[128 * 32];
  __shared__ u16 Btile[128 * 32];
  const int tid  = threadIdx.x;
  const int wid  = tid >> 6;
  const int lane = tid & 63;
  const int NXT = Ndim / 128;
  const int nwg = gridDim.x * gridDim.y;
  const int bid = xcd_swizzle(blockIdx.y * gridDim.x + blockIdx.x, nwg);
  const int bn = bid % NXT, bm = bid / NXT;
  const int wm = wid >> 1, wn = wid & 1;
  const int l4  = lane >> 4, l15 = lane & 15;
  f32x4 acc[4][4];
  #pragma unroll
  for (int i = 0; i < 4; ++i)
    #pragma unroll
    for (int j = 0; j < 4; ++j) acc[i][j] = {0.f, 0.f, 0.f, 0.f};
  const int srow = lane >> 2;
  const int scol = (lane & 3) * 8;
  for (int k0 = 0; k0 < Kdim; k0 += 32) {
    __syncthreads();
    #pragma unroll
    for (int i = 0; i < 2; ++i) {
      int c = wid * 2 + i;
      gload_lds16(A  + (size_t)(bm * 128 + c * 16 + srow) * Kdim + k0 + scol, &Atile[c * 512]);
      gload_lds16(Bt + (size_t)(bn * 128 + c * 16 + srow) * Kdim + k0 + scol, &Btile[c * 512]);
    }
    __syncthreads();
    short8 af[4], bf[4];
    #pragma unroll
    for (int mi = 0; mi < 4; ++mi)
      af[mi] = *(const short8*)&Atile[(wm * 64 + mi * 16 + l15) * 32 + l4 * 8];
    #pragma unroll
    for (int ni = 0; ni < 4; ++ni)
      bf[ni] = *(const short8*)&Btile[(wn * 64 + ni * 16 + l15) * 32 + l4 * 8];
    #pragma unroll
    for (int mi = 0; mi < 4; ++mi)
      #pragma unroll
      for (int ni = 0; ni < 4; ++ni)
        acc[mi][ni] = __builtin_amdgcn_mfma_f32_16x16x32_bf16(af[mi], bf[ni], acc[mi][ni], 0, 0, 0);
  }
  const int cm0 = bm * 128 + wm * 64;
  const int cn0 = bn * 128 + wn * 64;
  float bv[4];
  #pragma unroll
  for (int ni = 0; ni < 4; ++ni) bv[ni] = bias[cn0 + ni * 16 + l15];
  #pragma unroll
  for (int mi = 0; mi < 4; ++mi) {
    #pragma unroll
    for (int r = 0; r < 4; ++r) {
      const int row = cm0 + mi * 16 + l4 * 4 + r;
      float gv = 0.f;
      if (EPI != 0) gv = gate[(size_t)row * 8 + expert];
      #pragma unroll
      for (int ni = 0; ni < 4; ++ni) {
        const int col = cn0 + ni * 16 + l15;
        float v = acc[mi][ni][r] + bv[ni];
        if (EPI == 0)      Hout[(size_t)row * Ndim + col] = f2bf(fmaxf(v, 0.f));
        else if (EPI == 1) Cout[(size_t)row * Ndim + col] = gv * v;
        else               Cout[(size_t)row * Ndim + col] += gv * v;
      }
    }
  }
}

// ---------- launch ----------
extern "C" void kernel_launch(void* const* d_in, const int* in_sizes, int n_in,
                              void* d_out, int out_size, void* d_ws, size_t ws_size,
                              hipStream_t stream) {
  const float* x  = (const float*)d_in[0];
  const float* Wr = (const float*)d_in[1];
  const float* br = (const float*)d_in[2];
  const float* W1 = (const float*)d_in[3];
  const float* b1 = (const float*)d_in[4];
  const float* W2 = (const float*)d_in[5];
  const float* b2 = (const float*)d_in[6];
  float* out = (float*)d_out;

  const size_t sz_gate = (size_t)BT * EDIM * 4;            // 128 KB
  const size_t sz_xb   = (size_t)BT * HDIM * 2;            // 8 MB
  const size_t sz_w1t  = (size_t)EDIM * FDIM * HDIM * 2;   // 64 MB
  const size_t sz_w2t  = (size_t)EDIM * HDIM * FDIM * 2;   // 64 MB
  const size_t sz_hall = (size_t)BT * KCAT * 2;            // 256 MB
  const size_t need_primary = sz_gate + sz_xb + sz_w1t + sz_w2t + sz_hall;

  char* p = (char*)d_ws;
  float* gate = (float*)p; p += sz_gate;
  u16* xb   = (u16*)p;     p += sz_xb;
  u16* w1t  = (u16*)p;     char* w1t_region = (char*)w1t; p += sz_w1t;
  u16* w2t  = (u16*)p;     p += sz_w2t;

  router_kernel<<<BT / 4, 256, 0, stream>>>(x, Wr, br, gate);
  cast_x_kernel<<<(BT * HDIM) / (256 * 8), 256, 0, stream>>>(x, xb);
  // W1 (E,H,F) -> w1t[e][f][h]  (rstride=H, estride=F*H)
  transpose_cast_kernel<<<dim3(FDIM / 32, HDIM / 32, EDIM), dim3(32, 8), 0, stream>>>(
      W1, w1t, HDIM, FDIM, HDIM, (size_t)FDIM * HDIM);

  if (ws_size >= need_primary) {
    u16* h_all = (u16*)p;                       // (BT, KCAT) bf16
    float* part = (float*)w1t_region;           // 4 x (BT,H) f32, aliases w1t after G1
    // W2 (E,F,H) -> B'[n][e*F+f]  (rstride=KCAT, estride=F)
    transpose_cast_kernel<<<dim3(HDIM / 32, FDIM / 32, EDIM), dim3(32, 8), 0, stream>>>(
        W2, w2t, FDIM, HDIM, KCAT, FDIM);
    // GEMM1: all experts, h_all[row, e*F+col] = bf16(gate*relu(x@W1_e + b1_e))
    gemm256<0><<<dim3(16, 16, 8), 512, 0, stream>>>(xb, w1t, b1, gate, h_all, nullptr);
    // GEMM2: (g.h) @ concat(W2), split-K x4 -> part
    gemm256<1><<<dim3(4, 16, 4), 512, 0, stream>>>(h_all, w2t, nullptr, nullptr, nullptr, part);
    // out = sum_z part + sum_e g_e * b2_e
    reduce_kernel<<<(BT * HDIM) / (256 * 4), 256, 0, stream>>>(part, gate, b2, out);
  } else {
    // -------- fallback: R2-proven path --------
    u16* h = (u16*)p;   // (BT, F) one expert, 32 MB
    transpose_cast_kernel<<<dim3(HDIM / 32, FDIM / 32, EDIM), dim3(32, 8), 0, stream>>>(
        W2, w2t, FDIM, HDIM, FDIM, (size_t)HDIM * FDIM);
    for (int e = 0; e < EDIM; ++e) {
      gemm_fb<FDIM, HDIM, 0><<<dim3(FDIM / 128, BT / 128), 256, 0, stream>>>(
          xb, w1t + (size_t)e * FDIM * HDIM, b1 + (size_t)e * FDIM, nullptr, 0, h, nullptr);
      if (e == 0)
        gemm_fb<HDIM, FDIM, 1><<<dim3(HDIM / 128, BT / 128), 256, 0, stream>>>(
            h, w2t + (size_t)e * HDIM * FDIM, b2 + (size_t)e * HDIM, gate, e, nullptr, out);
      else
        gemm_fb<HDIM, FDIM, 2><<<dim3(HDIM / 128, BT / 128), 256, 0, stream>>>(
            h, w2t + (size_t)e * HDIM * FDIM, b2 + (size_t)e * HDIM, gate, e, nullptr, out);
    }
  }
}

// Round 5
// 659.277 us; speedup vs baseline: 1.7704x; 1.1016x over previous
//
#include <hip/hip_runtime.h>
#include <hip/hip_bf16.h>
#include <stdint.h>

// Problem dims (B=2, T=2048, H=1024, F=4096, E=8)
#define BT   4096
#define HDIM 1024
#define FDIM 4096
#define EDIM 8
#define TOPP 0.8f
#define KCAT (EDIM * FDIM)   // 32768 concatenated K for GEMM2

typedef unsigned short u16;
typedef __attribute__((ext_vector_type(8))) short  short8;
typedef __attribute__((ext_vector_type(8))) unsigned short ushort8;
typedef __attribute__((ext_vector_type(4))) float  f32x4;

// ---------- helpers ----------
__device__ __forceinline__ u16 f2bf(float f) {
  uint32_t u = __builtin_bit_cast(uint32_t, f);
  uint32_t r = u + 0x7FFFu + ((u >> 16) & 1u);   // RNE
  return (u16)(r >> 16);
}

__device__ __forceinline__ void gload_lds16(const void* g, void* l) {
  __builtin_amdgcn_global_load_lds(
      (const __attribute__((address_space(1))) uint32_t*)g,
      (__attribute__((address_space(3))) uint32_t*)l, 16, 0, 0);
}

#define VMWAIT2() asm volatile("s_waitcnt vmcnt(2)" ::: "memory")
#define VMWAIT0() asm volatile("s_waitcnt vmcnt(0)" ::: "memory")
#define BAR()     asm volatile("s_barrier" ::: "memory")

// Bijective XCD-aware swizzle (m204)
__device__ __forceinline__ int xcd_swizzle(int bid, int nwg) {
  const int nx = 8;
  int q = nwg / nx, r = nwg % nx;
  int xcd = bid % nx, lin = bid / nx;
  int base = (xcd < r) ? xcd * (q + 1) : r * (q + 1) + (xcd - r) * q;
  return base + lin;
}

// ---------- router: probs -> top-p gate (stable argsort semantics) ----------
__global__ __launch_bounds__(256) void router_kernel(
    const float* __restrict__ x, const float* __restrict__ Wr,
    const float* __restrict__ br, float* __restrict__ gate) {
  const int wid  = threadIdx.x >> 6;
  const int lane = threadIdx.x & 63;
  const int token = blockIdx.x * 4 + wid;
  const float* xr = x + (size_t)token * HDIM;

  float p[8] = {0.f,0.f,0.f,0.f,0.f,0.f,0.f,0.f};
  #pragma unroll
  for (int j = 0; j < 16; ++j) {
    int hh = lane * 16 + j;
    float xv = xr[hh];
    const float* wrow = Wr + (size_t)hh * 8;
    #pragma unroll
    for (int e = 0; e < 8; ++e) p[e] += xv * wrow[e];
  }
  #pragma unroll
  for (int off = 32; off > 0; off >>= 1) {
    #pragma unroll
    for (int e = 0; e < 8; ++e) p[e] += __shfl_xor(p[e], off, 64);
  }
  float mx = -1e30f;
  #pragma unroll
  for (int e = 0; e < 8; ++e) { p[e] += br[e]; mx = fmaxf(mx, p[e]); }
  float s = 0.f;
  #pragma unroll
  for (int e = 0; e < 8; ++e) { p[e] = expf(p[e] - mx); s += p[e]; }
  float inv = 1.0f / s;
  #pragma unroll
  for (int e = 0; e < 8; ++e) p[e] *= inv;

  if (lane == 0) {
    float g[8];
    #pragma unroll
    for (int e = 0; e < 8; ++e) {
      float pe = p[e];
      float cum = pe; int rank = 0;
      #pragma unroll
      for (int e2 = 0; e2 < 8; ++e2) {
        if (e2 == e) continue;
        bool before = (p[e2] > pe) || (p[e2] == pe && e2 < e);
        if (before) { cum += p[e2]; rank++; }
      }
      bool keep = (cum < TOPP) || (rank == 0);
      g[e] = keep ? pe : 0.f;
    }
    float* gp = gate + (size_t)token * 8;
    #pragma unroll
    for (int e = 0; e < 8; ++e) gp[e] = g[e];
  }
}

// ---------- cast x f32 -> bf16 ----------
__global__ __launch_bounds__(256) void cast_x_kernel(
    const float* __restrict__ in, u16* __restrict__ out) {
  int i = (blockIdx.x * 256 + threadIdx.x) * 8;
  float4 a = *(const float4*)(in + i);
  float4 b = *(const float4*)(in + i + 4);
  ushort8 o;
  o[0] = f2bf(a.x); o[1] = f2bf(a.y); o[2] = f2bf(a.z); o[3] = f2bf(a.w);
  o[4] = f2bf(b.x); o[5] = f2bf(b.y); o[6] = f2bf(b.z); o[7] = f2bf(b.w);
  *(ushort8*)(out + i) = o;
}

// ---------- transpose + cast: per-expert (R,C) f32 -> out[e*estride + c*rstride + r] bf16
__global__ __launch_bounds__(256) void transpose_cast_kernel(
    const float* __restrict__ in, u16* __restrict__ out, int R, int C,
    size_t rstride, size_t estride) {
  __shared__ float tile[32][33];
  const int e = blockIdx.z;
  const float* ip = in + (size_t)e * R * C;
  u16* op = out + (size_t)e * estride;
  int x  = blockIdx.x * 32 + threadIdx.x;   // C coord
  int y0 = blockIdx.y * 32;                 // R tile base
  int ty = threadIdx.y;                     // 0..7
  #pragma unroll
  for (int j = 0; j < 32; j += 8)
    tile[ty + j][threadIdx.x] = ip[(size_t)(y0 + ty + j) * C + x];
  __syncthreads();
  int xo  = y0 + threadIdx.x;               // R coord (contiguous on out)
  int yo0 = blockIdx.x * 32;
  #pragma unroll
  for (int j = 0; j < 32; j += 8)
    op[(size_t)(yo0 + ty + j) * rstride + xo] = f2bf(tile[threadIdx.x][ty + j]);
}

// ======================================================================
// 256x256-tile GEMM, BK=64, 8 waves (2M x 4N, wave-tile 128x64),
// m201-style 4-phase/K-tile schedule: per phase {ds_read cluster +
// stage issue + barrier + 16 MFMA (setprio) + barrier}, counted vmcnt(2)
// once per K-tile (phase D), XOR-granule LDS swizzle (conflict-free).
// Race proof: every stage target's last reader is behind >=1 barrier:
//   A-hi/B-hi(u+1)@A, B-lo(u+1)@B -> other buf; A-lo(u+2)@D after C-end
//   barrier (all a[s1] reads of buf p complete). Gate vmcnt(2) at D =
//   everything except the just-issued A-lo(u+2) has landed.
// MODE 0 (GEMM1): h_all[row, e*F+col] = bf16(gate*relu(x@W1_e + b1))
// MODE 1 (GEMM2): part[z] = A'(BT,KCAT) x B'^T  (K-split z, f32)
// ======================================================================
template <int MODE>
__global__ __launch_bounds__(512, 2) void gemm256(
    const u16* __restrict__ A0, const u16* __restrict__ B0,
    const float* __restrict__ bias, const float* __restrict__ gate,
    u16* __restrict__ hout, float* __restrict__ part) {
  // LDS bytes: A[p][row][gran]: p*32768 + row*128 + gran*16   (0..65535)
  //            B[p][row][gran]: 65536 + p*32768 + row*128 + gran*16
  __shared__ u16 lds[65536];   // 128 KiB

  constexpr int NXT  = (MODE == 0 ? 16 : 4);
  constexpr int NYT  = 16;
  constexpr int NZ   = (MODE == 0 ? 8 : 4);
  constexpr int NT   = (MODE == 0 ? HDIM / 64 : (KCAT / NZ) / 64);  // 16 / 128
  const size_t Kstr  = (MODE == 0 ? (size_t)HDIM : (size_t)KCAT);

  const int tid  = threadIdx.x;
  const int wid  = tid >> 6;
  const int lane = tid & 63;

  int lin = (blockIdx.z * gridDim.y + blockIdx.y) * gridDim.x + blockIdx.x;
  lin = xcd_swizzle(lin, NXT * NYT * NZ);
  const int bn = lin % NXT; lin /= NXT;
  const int bm = lin % NYT; lin /= NYT;
  const int bz = lin;                       // expert (MODE0) or k-split (MODE1)

  const u16* Abase = A0 + (size_t)bm * 256 * Kstr
                        + (MODE == 0 ? 0 : (size_t)bz * (KCAT / NZ));
  const u16* Bbase = (MODE == 0 ? B0 + (size_t)bz * FDIM * HDIM
                                : B0 + (size_t)bz * (KCAT / NZ))
                        + (size_t)bn * 256 * Kstr;

  // ---- staging geometry: thread covers (row = tid>>3 [+64], granule = tid&7)
  const int srow = tid >> 3;                         // 0..63
  const int sg   = tid & 7;                          // dest granule
  const int scol = (sg ^ (srow & 7)) * 8;            // pre-swizzled src col (u16)

  // STAGEH(T, WH): stage half-tile WH (0=A-lo,1=A-hi,2=B-lo,3=B-hi) of K-tile T
  #define STAGEH(T, WH) do {                                              \
    const int _p = (T) & 1;                                               \
    const u16* _gb = ((WH) < 2 ? Abase : Bbase);                          \
    const size_t _r0 = (size_t)(((WH) & 1) * 128 + srow);                 \
    const size_t _cc = (size_t)(T) * 64 + scol;                           \
    char* _d = (char*)lds + ((WH) >= 2 ? 65536 : 0) + _p * 32768          \
               + ((WH) & 1) * 16384 + tid * 16;                           \
    gload_lds16(_gb + _r0 * Kstr + _cc, _d);                              \
    gload_lds16(_gb + (_r0 + 64) * Kstr + _cc, _d + 8192);                \
  } while (0)

  const int wm = wid >> 2, wn = wid & 3;   // 2M x 4N waves, each 128x64
  const int l4 = lane >> 4, l15 = lane & 15;

  f32x4 acc[8][4];
  #pragma unroll
  for (int i = 0; i < 8; ++i)
    #pragma unroll
    for (int j = 0; j < 4; ++j) acc[i][j] = {0.f, 0.f, 0.f, 0.f};

  // swizzled LDS read byte-offsets (p-independent part)
  int aof0[8], aof1[8], bof0[4], bof1[4];
  #pragma unroll
  for (int mi = 0; mi < 8; ++mi) {
    int row = wm * 128 + mi * 16 + l15;
    aof0[mi] = row * 128 + ((l4       ^ (row & 7)) * 16);
    aof1[mi] = row * 128 + (((4 + l4) ^ (row & 7)) * 16);
  }
  #pragma unroll
  for (int ni = 0; ni < 4; ++ni) {
    int row = wn * 64 + ni * 16 + l15;
    bof0[ni] = row * 128 + ((l4       ^ (row & 7)) * 16);
    bof1[ni] = row * 128 + (((4 + l4) ^ (row & 7)) * 16);
  }

  #define LD(off) (*(const short8*)((const char*)lds + (off)))

  #define DO_MFMA(N0) do {                                                \
    asm volatile("s_waitcnt lgkmcnt(0)" ::: "memory");                    \
    __builtin_amdgcn_s_setprio(1);                                        \
    _Pragma("unroll")                                                     \
    for (int mi = 0; mi < 8; ++mi) {                                      \
      acc[mi][N0]     = __builtin_amdgcn_mfma_f32_16x16x32_bf16(          \
          a_[mi], b_[N0],     acc[mi][N0],     0, 0, 0);                  \
      acc[mi][N0 + 1] = __builtin_amdgcn_mfma_f32_16x16x32_bf16(          \
          a_[mi], b_[N0 + 1], acc[mi][N0 + 1], 0, 0, 0);                  \
    }                                                                     \
    __builtin_amdgcn_s_setprio(0);                                        \
  } while (0)

  // ---- prologue: K0 fully + A-lo(K1); gate all of K0 ----
  STAGEH(0, 0); STAGEH(0, 1); STAGEH(0, 2); STAGEH(0, 3);
  STAGEH(1, 0);
  VMWAIT2();    // outstanding = A-lo(K1) only -> K0 landed
  BAR();

  for (int u = 0; u < NT; ++u) {
    const int pA = (u & 1) * 32768;
    const int pB = 65536 + (u & 1) * 32768;
    short8 a_[8], b_[4];

    // ---- phase A: reads a[s0], b0-1[s0]; stage A-hi,B-hi(u+1) ----
    #pragma unroll
    for (int mi = 0; mi < 8; ++mi) a_[mi] = LD(pA + aof0[mi]);
    b_[0] = LD(pB + bof0[0]); b_[1] = LD(pB + bof0[1]);
    if (u + 1 < NT) { STAGEH(u + 1, 1); STAGEH(u + 1, 3); }
    BAR();
    DO_MFMA(0);
    BAR();

    // ---- phase B: reads b2-3[s0]; stage B-lo(u+1) ----
    b_[2] = LD(pB + bof0[2]); b_[3] = LD(pB + bof0[3]);
    if (u + 1 < NT) STAGEH(u + 1, 2);
    BAR();
    DO_MFMA(2);
    BAR();

    // ---- phase C: reads a[s1], b0-1[s1] ----
    #pragma unroll
    for (int mi = 0; mi < 8; ++mi) a_[mi] = LD(pA + aof1[mi]);
    b_[0] = LD(pB + bof1[0]); b_[1] = LD(pB + bof1[1]);
    BAR();
    DO_MFMA(0);
    BAR();

    // ---- phase D: reads b2-3[s1]; stage A-lo(u+2); counted gate ----
    b_[2] = LD(pB + bof1[2]); b_[3] = LD(pB + bof1[3]);
    if (u + 2 < NT) STAGEH(u + 2, 0);
    if (u + 1 < NT) { if (u + 2 < NT) VMWAIT2(); else VMWAIT0(); }
    BAR();
    DO_MFMA(2);
    BAR();
  }

  // ---------------- epilogue ----------------
  const int rowbase = bm * 256 + wm * 128;
  const int colbase = bn * 256 + wn * 64;

  if constexpr (MODE == 0) {
    float bv[4];
    #pragma unroll
    for (int ni = 0; ni < 4; ++ni)
      bv[ni] = bias[(size_t)bz * FDIM + colbase + ni * 16 + l15];
    #pragma unroll
    for (int mi = 0; mi < 8; ++mi) {
      #pragma unroll
      for (int r = 0; r < 4; ++r) {
        const int row = rowbase + mi * 16 + l4 * 4 + r;
        const float gv = gate[(size_t)row * 8 + bz];
        #pragma unroll
        for (int ni = 0; ni < 4; ++ni) {
          const int col = colbase + ni * 16 + l15;
          float v = fmaxf(acc[mi][ni][r] + bv[ni], 0.f);
          hout[(size_t)row * KCAT + (size_t)bz * FDIM + col] = f2bf(gv * v);
        }
      }
    }
  } else {
    float* pp = part + (size_t)bz * BT * HDIM;
    #pragma unroll
    for (int mi = 0; mi < 8; ++mi) {
      #pragma unroll
      for (int r = 0; r < 4; ++r) {
        const int row = rowbase + mi * 16 + l4 * 4 + r;
        #pragma unroll
        for (int ni = 0; ni < 4; ++ni) {
          const int col = colbase + ni * 16 + l15;
          pp[(size_t)row * HDIM + col] = acc[mi][ni][r];
        }
      }
    }
  }
  #undef STAGEH
  #undef LD
  #undef DO_MFMA
}

// ---------- reduce: out = sum_z part[z] + sum_e gate[row][e]*b2[e][col] ----------
__global__ __launch_bounds__(256) void reduce_kernel(
    const float* __restrict__ part, const float* __restrict__ gate,
    const float* __restrict__ b2, float* __restrict__ out) {
  const int i = (blockIdx.x * 256 + threadIdx.x) * 4;
  const int row = i >> 10, col = i & 1023;
  float4 s = *(const float4*)(part + i);
  #pragma unroll
  for (int z = 1; z < 4; ++z) {
    float4 t = *(const float4*)(part + (size_t)z * BT * HDIM + i);
    s.x += t.x; s.y += t.y; s.z += t.z; s.w += t.w;
  }
  const float* g = gate + (size_t)row * 8;
  #pragma unroll
  for (int e = 0; e < 8; ++e) {
    float ge = g[e];
    float4 bv = *(const float4*)(b2 + (size_t)e * HDIM + col);
    s.x += ge * bv.x; s.y += ge * bv.y; s.z += ge * bv.z; s.w += ge * bv.w;
  }
  *(float4*)(out + i) = s;
}

// ======================================================================
// Fallback (R2-proven): 128x128-tile per-expert GEMMs, used if ws too small
// ======================================================================
template <int Ndim, int Kdim, int EPI>
__global__ __launch_bounds__(256) void gemm_fb(
    const u16* __restrict__ A, const u16* __restrict__ Bt,
    const float* __restrict__ bias, const float* __restrict__ gate,
    int expert, u16* __restrict__ Hout, float* __restrict__ Cout) {
  __shared__ u16 Atile[128 * 32];
  __shared__ u16 Btile[128 * 32];
  const int tid  = threadIdx.x;
  const int wid  = tid >> 6;
  const int lane = tid & 63;
  const int NXT = Ndim / 128;
  const int nwg = gridDim.x * gridDim.y;
  const int bid = xcd_swizzle(blockIdx.y * gridDim.x + blockIdx.x, nwg);
  const int bn = bid % NXT, bm = bid / NXT;
  const int wm = wid >> 1, wn = wid & 1;
  const int l4  = lane >> 4, l15 = lane & 15;
  f32x4 acc[4][4];
  #pragma unroll
  for (int i = 0; i < 4; ++i)
    #pragma unroll
    for (int j = 0; j < 4; ++j) acc[i][j] = {0.f, 0.f, 0.f, 0.f};
  const int srow = lane >> 2;
  const int scol = (lane & 3) * 8;
  for (int k0 = 0; k0 < Kdim; k0 += 32) {
    __syncthreads();
    #pragma unroll
    for (int i = 0; i < 2; ++i) {
      int c = wid * 2 + i;
      gload_lds16(A  + (size_t)(bm * 128 + c * 16 + srow) * Kdim + k0 + scol, &Atile[c * 512]);
      gload_lds16(Bt + (size_t)(bn * 128 + c * 16 + srow) * Kdim + k0 + scol, &Btile[c * 512]);
    }
    __syncthreads();
    short8 af[4], bf[4];
    #pragma unroll
    for (int mi = 0; mi < 4; ++mi)
      af[mi] = *(const short8*)&Atile[(wm * 64 + mi * 16 + l15) * 32 + l4 * 8];
    #pragma unroll
    for (int ni = 0; ni < 4; ++ni)
      bf[ni] = *(const short8*)&Btile[(wn * 64 + ni * 16 + l15) * 32 + l4 * 8];
    #pragma unroll
    for (int mi = 0; mi < 4; ++mi)
      #pragma unroll
      for (int ni = 0; ni < 4; ++ni)
        acc[mi][ni] = __builtin_amdgcn_mfma_f32_16x16x32_bf16(af[mi], bf[ni], acc[mi][ni], 0, 0, 0);
  }
  const int cm0 = bm * 128 + wm * 64;
  const int cn0 = bn * 128 + wn * 64;
  float bv[4];
  #pragma unroll
  for (int ni = 0; ni < 4; ++ni) bv[ni] = bias[cn0 + ni * 16 + l15];
  #pragma unroll
  for (int mi = 0; mi < 4; ++mi) {
    #pragma unroll
    for (int r = 0; r < 4; ++r) {
      const int row = cm0 + mi * 16 + l4 * 4 + r;
      float gv = 0.f;
      if (EPI != 0) gv = gate[(size_t)row * 8 + expert];
      #pragma unroll
      for (int ni = 0; ni < 4; ++ni) {
        const int col = cn0 + ni * 16 + l15;
        float v = acc[mi][ni][r] + bv[ni];
        if (EPI == 0)      Hout[(size_t)row * Ndim + col] = f2bf(fmaxf(v, 0.f));
        else if (EPI == 1) Cout[(size_t)row * Ndim + col] = gv * v;
        else               Cout[(size_t)row * Ndim + col] += gv * v;
      }
    }
  }
}

// ---------- launch ----------
extern "C" void kernel_launch(void* const* d_in, const int* in_sizes, int n_in,
                              void* d_out, int out_size, void* d_ws, size_t ws_size,
                              hipStream_t stream) {
  const float* x  = (const float*)d_in[0];
  const float* Wr = (const float*)d_in[1];
  const float* br = (const float*)d_in[2];
  const float* W1 = (const float*)d_in[3];
  const float* b1 = (const float*)d_in[4];
  const float* W2 = (const float*)d_in[5];
  const float* b2 = (const float*)d_in[6];
  float* out = (float*)d_out;

  const size_t sz_gate = (size_t)BT * EDIM * 4;            // 128 KB
  const size_t sz_xb   = (size_t)BT * HDIM * 2;            // 8 MB
  const size_t sz_w1t  = (size_t)EDIM * FDIM * HDIM * 2;   // 64 MB
  const size_t sz_w2t  = (size_t)EDIM * HDIM * FDIM * 2;   // 64 MB
  const size_t sz_hall = (size_t)BT * KCAT * 2;            // 256 MB
  const size_t need_primary = sz_gate + sz_xb + sz_w1t + sz_w2t + sz_hall;

  char* p = (char*)d_ws;
  float* gate = (float*)p; p += sz_gate;
  u16* xb   = (u16*)p;     p += sz_xb;
  u16* w1t  = (u16*)p;     char* w1t_region = (char*)w1t; p += sz_w1t;
  u16* w2t  = (u16*)p;     p += sz_w2t;

  router_kernel<<<BT / 4, 256, 0, stream>>>(x, Wr, br, gate);
  cast_x_kernel<<<(BT * HDIM) / (256 * 8), 256, 0, stream>>>(x, xb);
  // W1 (E,H,F) -> w1t[e][f][h]  (rstride=H, estride=F*H)
  transpose_cast_kernel<<<dim3(FDIM / 32, HDIM / 32, EDIM), dim3(32, 8), 0, stream>>>(
      W1, w1t, HDIM, FDIM, HDIM, (size_t)FDIM * HDIM);

  if (ws_size >= need_primary) {
    u16* h_all = (u16*)p;                       // (BT, KCAT) bf16
    float* part = (float*)w1t_region;           // 4 x (BT,H) f32, aliases w1t after G1
    // W2 (E,F,H) -> B'[n][e*F+f]  (rstride=KCAT, estride=F)
    transpose_cast_kernel<<<dim3(HDIM / 32, FDIM / 32, EDIM), dim3(32, 8), 0, stream>>>(
        W2, w2t, FDIM, HDIM, KCAT, FDIM);
    // GEMM1: all experts, h_all[row, e*F+col] = bf16(gate*relu(x@W1_e + b1_e))
    gemm256<0><<<dim3(16, 16, 8), 512, 0, stream>>>(xb, w1t, b1, gate, h_all, nullptr);
    // GEMM2: (g.h) @ concat(W2), split-K x4 -> part
    gemm256<1><<<dim3(4, 16, 4), 512, 0, stream>>>(h_all, w2t, nullptr, nullptr, nullptr, part);
    // out = sum_z part + sum_e g_e * b2_e
    reduce_kernel<<<(BT * HDIM) / (256 * 4), 256, 0, stream>>>(part, gate, b2, out);
  } else {
    // -------- fallback: R2-proven path --------
    u16* h = (u16*)p;   // (BT, F) one expert, 32 MB
    transpose_cast_kernel<<<dim3(HDIM / 32, FDIM / 32, EDIM), dim3(32, 8), 0, stream>>>(
        W2, w2t, FDIM, HDIM, FDIM, (size_t)HDIM * FDIM);
    for (int e = 0; e < EDIM; ++e) {
      gemm_fb<FDIM, HDIM, 0><<<dim3(FDIM / 128, BT / 128), 256, 0, stream>>>(
          xb, w1t + (size_t)e * FDIM * HDIM, b1 + (size_t)e * FDIM, nullptr, 0, h, nullptr);
      if (e == 0)
        gemm_fb<HDIM, FDIM, 1><<<dim3(HDIM / 128, BT / 128), 256, 0, stream>>>(
            h, w2t + (size_t)e * HDIM * FDIM, b2 + (size_t)e * HDIM, gate, e, nullptr, out);
      else
        gemm_fb<HDIM, FDIM, 2><<<dim3(HDIM / 128, BT / 128), 256, 0, stream>>>(
            h, w2t + (size_t)e * HDIM * FDIM, b2 + (size_t)e * HDIM, gate, e, nullptr, out);
    }
  }
}